// Round 11
// baseline (267.394 us; speedup 1.0000x reference)
//
#include <hip/hip_runtime.h>
#include <hip/hip_bf16.h>
#include <math.h>

#define NE 8
#define TOPK 2
#define HD 1024
#define FD 4096
#define NTOK 4096
#define NASSIGN 8192
#define CAP 1024

typedef __attribute__((ext_vector_type(8))) short short8;
typedef __attribute__((ext_vector_type(4))) float f32x4;
typedef __attribute__((ext_vector_type(4))) unsigned short us4;
typedef __attribute__((ext_vector_type(4))) unsigned int u32x4;

__device__ __forceinline__ unsigned short f2bf(float f) {
  unsigned u = __float_as_uint(f);
  u += 0x7fffu + ((u >> 16) & 1u);
  return (unsigned short)(u >> 16);
}

__device__ __forceinline__ void load_lds16(const void* g, void* l) {
  __builtin_amdgcn_global_load_lds((const __attribute__((address_space(1))) void*)g,
                                   (__attribute__((address_space(3))) void*)l, 16, 0, 0);
}

// XOR swizzle (proven r2-r10): permute 16B granules by (row>>1)&3; involution.
__device__ __forceinline__ unsigned swz(unsigned b) {
  return b ^ (((b >> 7) & 3u) << 4);
}

// ---------------- transpose + fp32->bf16 convert: W[R][C] -> Wt[C][R] ----------------
// r1-form, ~6 TB/s. Do NOT fuse or reorder the grid mapping (r8 regression).
__global__ __launch_bounds__(256)
void transpose_convert(const float* __restrict__ W, unsigned short* __restrict__ Wt,
                       int R, int C) {
  __shared__ float tile[64][65];
  int e = blockIdx.z;
  W  += (size_t)e * R * C;
  Wt += (size_t)e * R * C;
  int c0 = blockIdx.x * 64, r0 = blockIdx.y * 64;
  int tx = threadIdx.x & 15, ty = threadIdx.x >> 4;
#pragma unroll
  for (int i = 0; i < 4; ++i) {
    f32x4 v = *(const f32x4*)(W + (size_t)(r0 + ty + i * 16) * C + c0 + tx * 4);
    tile[ty + i * 16][tx * 4 + 0] = v.x;
    tile[ty + i * 16][tx * 4 + 1] = v.y;
    tile[ty + i * 16][tx * 4 + 2] = v.z;
    tile[ty + i * 16][tx * 4 + 3] = v.w;
  }
  __syncthreads();
#pragma unroll
  for (int i = 0; i < 4; ++i) {
    int c = ty + i * 16;
    us4 o;
    o.x = f2bf(tile[tx * 4 + 0][c]);
    o.y = f2bf(tile[tx * 4 + 1][c]);
    o.z = f2bf(tile[tx * 4 + 2][c]);
    o.w = f2bf(tile[tx * 4 + 3][c]);
    *(us4*)(Wt + (size_t)(c0 + c) * R + r0 + tx * 4) = o;
  }
}

// ---------------- routing: stable counting sort metadata ----------------
__global__ __launch_bounds__(1024)
void routing_kernel(const int* __restrict__ te, int* __restrict__ rankA,
                    int* __restrict__ srcTok, int* __restrict__ counts) {
  __shared__ uint4 pref[1024];
  int t = threadIdx.x;
  int myTe[8];
  unsigned lc[4] = {0, 0, 0, 0};
#pragma unroll
  for (int j = 0; j < 8; ++j) {
    int ee = te[t * 8 + j];
    myTe[j] = ee;
    lc[ee >> 1] += 1u << ((ee & 1) * 16);
  }
  uint4 inc;
  inc.x = lc[0]; inc.y = lc[1]; inc.z = lc[2]; inc.w = lc[3];
  pref[t] = inc;
  __syncthreads();
  for (int d = 1; d < 1024; d <<= 1) {
    uint4 add;
    bool has = (t >= d);
    if (has) add = pref[t - d];
    __syncthreads();
    if (has) {
      inc.x += add.x; inc.y += add.y; inc.z += add.z; inc.w += add.w;
      pref[t] = inc;
    }
    __syncthreads();
  }
  unsigned ex[4] = {inc.x - lc[0], inc.y - lc[1], inc.z - lc[2], inc.w - lc[3]};
  uint4 tot = pref[1023];
  int run[8];
#pragma unroll
  for (int eidx = 0; eidx < 8; ++eidx)
    run[eidx] = (ex[eidx >> 1] >> ((eidx & 1) * 16)) & 0xffff;
#pragma unroll
  for (int j = 0; j < 8; ++j) {
    int ee = myTe[j];
    int r = run[ee]++;
    rankA[t * 8 + j] = r;
    if (r < CAP) srcTok[ee * CAP + r] = (t * 8 + j) >> 1;
  }
  if (t < 8) {
    unsigned tt[4] = {tot.x, tot.y, tot.z, tot.w};
    counts[t] = (tt[t >> 1] >> ((t & 1) * 16)) & 0xffff;
  }
}

// ---------------- gather x rows into bf16 buf[E][CAP][HD], zero pad ----------------
__global__ __launch_bounds__(128)
void gather_kernel(const float* __restrict__ x, const int* __restrict__ srcTok,
                   const int* __restrict__ counts, unsigned short* __restrict__ buf) {
  int row = blockIdx.x;
  int e = row >> 10;
  int c = row & (CAP - 1);
  int t = threadIdx.x;
  unsigned short* dst = buf + (size_t)row * HD + t * 8;
  if (c < counts[e]) {
    const float* src = x + (size_t)srcTok[row] * HD + t * 8;
    f32x4 v0 = *(const f32x4*)src;
    f32x4 v1 = *(const f32x4*)(src + 4);
    u32x4 o;
    o.x = f2bf(v0.x) | ((unsigned)f2bf(v0.y) << 16);
    o.y = f2bf(v0.z) | ((unsigned)f2bf(v0.w) << 16);
    o.z = f2bf(v1.x) | ((unsigned)f2bf(v1.y) << 16);
    o.w = f2bf(v1.z) | ((unsigned)f2bf(v1.w) << 16);
    *(u32x4*)dst = o;
  } else {
    u32x4 z = {0, 0, 0, 0};
    *(u32x4*)dst = z;
  }
}

// ---------------- 256x128 ring-3, 4-wave, 2-blocks/CU batched GEMM ----------------
// A[e][CAP][KTOT] bf16 row-major, Bt[e][NDIM][KTOT] bf16 row-major (= B^T).
// C = A @ Bt^T. 4 waves (2Mx2N), wave-tile 128x64 (same LDS-bytes/FLOP as the
// proven 256^2 config), BK=32, ring-3 LDS = 72KB -> 2 independent blocks/CU.
// Inter-block overlap (m114) hides each block's barrier/vmcnt drains.
// De-fenced loop (r9): compiler emits counted lgkmcnt per MFMA dep.
// Counted vmcnt(6) (stage t+2 in flight), exact tail ladder 6/0.
// OMODE: 1 = gelu->bf16, 2 = bf16 partials (split-K).
template <int KTOT, int NDIM, int OMODE, int KSPLIT>
__global__ __launch_bounds__(256, 2)
void gemm256x128(const unsigned short* __restrict__ Ab, const unsigned short* __restrict__ Bb,
                 void* __restrict__ Cv) {
  constexpr int KLOC = KTOT / KSPLIT;
  constexpr int NT = KLOC / 32;              // K-tiles, >= 4
  constexpr int GX = CAP / 256;              // 4
  constexpr int GY = NDIM / 128;
  constexpr int NWG = GX * GY * NE * KSPLIT;
  constexpr unsigned BUFB = 24576u;          // per buf: A 16KB + B 8KB
  __shared__ char smem[3 * 24576];

  int orig = blockIdx.x;
  int wg = (orig & 7) * (NWG / 8) + (orig >> 3);   // XCD-aware, NWG%8==0
  int bx = wg % GX;
  int by = (wg / GX) % GY;
  int zz = wg / (GX * GY);
  int ks = zz % KSPLIT;
  int e  = zz / KSPLIT;

  const unsigned short* A  = Ab + (size_t)e * CAP * KTOT;
  const unsigned short* Bt = Bb + (size_t)e * NDIM * KTOT;
  int bm = bx * 256, bn = by * 128;
  int kbase = ks * KLOC;

  int tid = threadIdx.x;
  int lane = tid & 63;
  int w = tid >> 6;                  // 0..3
  int wr = w >> 1, wc = w & 1;
  int l15 = lane & 15, lq = lane >> 4;

  // swizzled ds_read offsets: granule = lq ^ ((row>>1)&3)
  unsigned sw = (unsigned)((lq ^ ((l15 >> 1) & 3)) << 4);
  unsigned aoff[8], boff[4];
#pragma unroll
  for (int m = 0; m < 8; ++m)
    aoff[m] = (unsigned)((wr * 128 + m * 16 + l15) * 64) + sw;
#pragma unroll
  for (int n = 0; n < 4; ++n)
    boff[n] = 16384u + (unsigned)((wc * 64 + n * 16 + l15) * 64) + sw;

  // staging: A = 1024 granules (4/thread), B = 512 granules (2/thread);
  // pre-swizzled global source, linear LDS dest (proven mapping, 64B rows).
  const char* sA[4]; const char* sB[2];
  unsigned dA[4], dB[2];
#pragma unroll
  for (int j = 0; j < 4; ++j) {
    int idx = j * 256 + tid;
    int r_ = idx >> 2;
    unsigned kb = ((unsigned)(idx & 3) ^ (((unsigned)r_ >> 1) & 3u)) << 4;
    sA[j] = (const char*)(A + (size_t)(bm + r_) * KTOT + kbase) + kb;
    dA[j] = (unsigned)idx * 16;
  }
#pragma unroll
  for (int j = 0; j < 2; ++j) {
    int idx = j * 256 + tid;
    int r_ = idx >> 2;
    unsigned kb = ((unsigned)(idx & 3) ^ (((unsigned)r_ >> 1) & 3u)) << 4;
    sB[j] = (const char*)(Bt + (size_t)(bn + r_) * KTOT + kbase) + kb;
    dB[j] = 16384u + (unsigned)idx * 16;
  }

  // prologue: stage tiles 0 (buf0) and 1 (buf1)
#pragma unroll
  for (int tt = 0; tt < 2; ++tt) {
    char* db = smem + tt * BUFB;
#pragma unroll
    for (int j = 0; j < 4; ++j) load_lds16(sA[j] + tt * 64, db + dA[j]);
#pragma unroll
    for (int j = 0; j < 2; ++j) load_lds16(sB[j] + tt * 64, db + dB[j]);
  }
#pragma unroll
  for (int j = 0; j < 4; ++j) sA[j] += 128;
#pragma unroll
  for (int j = 0; j < 2; ++j) sB[j] += 128;
  asm volatile("s_waitcnt vmcnt(6)" ::: "memory");   // tile 0 landed
  __builtin_amdgcn_s_barrier();

  f32x4 acc[8][4] = {};

  unsigned cur = 0;
#pragma unroll 1
  for (int t = 0; t < NT; ++t) {
    const char* rb = smem + cur;
    short8 af[8], bf[4];
#pragma unroll
    for (int n = 0; n < 4; ++n) bf[n] = *(const short8*)(rb + boff[n]);
#pragma unroll
    for (int m = 0; m < 8; ++m) af[m] = *(const short8*)(rb + aoff[m]);
    if (t + 2 < NT) {                                 // stage t+2 into buf (t+2)%3
      unsigned stg = cur + 2 * BUFB;
      if (stg >= 3 * BUFB) stg -= 3 * BUFB;
      char* db = smem + stg;
#pragma unroll
      for (int j = 0; j < 4; ++j) { load_lds16(sA[j], db + dA[j]); sA[j] += 64; }
#pragma unroll
      for (int j = 0; j < 2; ++j) { load_lds16(sB[j], db + dB[j]); sB[j] += 64; }
    }
    // de-fenced: compiler inserts counted lgkmcnt per MFMA dependency.
#pragma unroll
    for (int m = 0; m < 8; ++m)
#pragma unroll
      for (int n = 0; n < 4; ++n)
        acc[m][n] = __builtin_amdgcn_mfma_f32_16x16x32_bf16(af[m], bf[n], acc[m][n], 0, 0, 0);
    // tile t+1 must be resident before next iteration begins.
    if (t + 2 < NT)       asm volatile("s_waitcnt vmcnt(6)" ::: "memory");
    else if (t == NT - 2) asm volatile("s_waitcnt vmcnt(0)" ::: "memory");
    asm volatile("s_barrier" ::: "memory");
    cur += BUFB;
    if (cur >= 3 * BUFB) cur = 0u;
  }

  // epilogue (proven C/D mapping)
  int r0 = bm + wr * 128 + lq * 4;
  int c0 = bn + wc * 64 + l15;
  if (OMODE == 1) {
    unsigned short* C = (unsigned short*)Cv + (size_t)e * CAP * NDIM;
#pragma unroll
    for (int m = 0; m < 8; ++m)
#pragma unroll
      for (int n = 0; n < 4; ++n)
#pragma unroll
        for (int j = 0; j < 4; ++j) {
          float v = acc[m][n][j];
          float y = 0.7978845608028654f * (v + 0.044715f * v * v * v);
          float g = v / (1.0f + __expf(-2.0f * y));   // tanh-gelu
          C[(size_t)(r0 + m * 16 + j) * NDIM + (c0 + n * 16)] = f2bf(g);
        }
  } else {
    unsigned short* C = (unsigned short*)Cv + ((size_t)ks * NE + e) * CAP * NDIM;
#pragma unroll
    for (int m = 0; m < 8; ++m)
#pragma unroll
      for (int n = 0; n < 4; ++n)
#pragma unroll
        for (int j = 0; j < 4; ++j)
          C[(size_t)(r0 + m * 16 + j) * NDIM + (c0 + n * 16)] = f2bf(acc[m][n][j]);
  }
}

// ---- scatter: out[t] = sum_k w[t,k]*(y0[e,r]+y1[e,r]) + bias ; y is bf16 partials ----
__global__ __launch_bounds__(128)
void scatter_kernel(const unsigned short* __restrict__ y, const int* __restrict__ te,
                    const int* __restrict__ rankA, const float* __restrict__ ew,
                    const float* __restrict__ bias, float* __restrict__ out) {
  int tk = blockIdx.x;
  int t = threadIdx.x;
  f32x4 a0 = *(const f32x4*)(bias + t * 8);
  f32x4 a1 = *(const f32x4*)(bias + t * 8 + 4);
#pragma unroll
  for (int k = 0; k < TOPK; ++k) {
    int a = tk * TOPK + k;
    int r = rankA[a];
    if (r < CAP) {
      float wgt = ew[a];
      size_t rowoff = ((size_t)te[a] * CAP + r) * HD + t * 8;
      u32x4 p0 = *(const u32x4*)(y + rowoff);
      u32x4 p1 = *(const u32x4*)(y + (size_t)NE * CAP * HD + rowoff);
#pragma unroll
      for (int j = 0; j < 2; ++j) {
        unsigned u0 = p0[j], u1 = p1[j];
        a0[2 * j]     += wgt * (__uint_as_float(u0 << 16) + __uint_as_float(u1 << 16));
        a0[2 * j + 1] += wgt * (__uint_as_float(u0 & 0xffff0000u) + __uint_as_float(u1 & 0xffff0000u));
      }
#pragma unroll
      for (int j = 0; j < 2; ++j) {
        unsigned u0 = p0[2 + j], u1 = p1[2 + j];
        a1[2 * j]     += wgt * (__uint_as_float(u0 << 16) + __uint_as_float(u1 << 16));
        a1[2 * j + 1] += wgt * (__uint_as_float(u0 & 0xffff0000u) + __uint_as_float(u1 & 0xffff0000u));
      }
    }
  }
  float* o = out + (size_t)tk * HD + t * 8;
  *(f32x4*)o = a0;
  *(f32x4*)(o + 4) = a1;
}

extern "C" void kernel_launch(void* const* d_in, const int* in_sizes, int n_in,
                              void* d_out, int out_size, void* d_ws, size_t ws_size,
                              hipStream_t stream) {
  const float* x    = (const float*)d_in[0];
  const float* ew   = (const float*)d_in[2];
  const int*   te   = (const int*)d_in[3];
  const float* w1   = (const float*)d_in[4];
  const float* w2   = (const float*)d_in[5];
  const float* bias = (const float*)d_in[6];
  float* out = (float*)d_out;

  unsigned short* w1t  = (unsigned short*)d_ws;                 // [E][F][H] bf16  64MB
  unsigned short* w2t  = w1t + (size_t)NE * HD * FD;            // [E][H][F] bf16  64MB
  unsigned short* bufg = w2t + (size_t)NE * HD * FD;            // [E][CAP][H]     16MB
  unsigned short* hbuf = bufg + (size_t)NE * CAP * HD;          // [E][CAP][F]     64MB
  unsigned short* ybuf = w1t;                                   // alias (w1t dead): [2][E][CAP][H] bf16 32MB
  int* rankA  = (int*)(hbuf + (size_t)NE * CAP * FD);
  int* srcTok = rankA + NASSIGN;
  int* counts = srcTok + NE * CAP;

  transpose_convert<<<dim3(FD / 64, HD / 64, NE), 256, 0, stream>>>(w1, w1t, HD, FD);
  transpose_convert<<<dim3(HD / 64, FD / 64, NE), 256, 0, stream>>>(w2, w2t, FD, HD);
  routing_kernel<<<1, 1024, 0, stream>>>(te, rankA, srcTok, counts);
  gather_kernel<<<NE * CAP, 128, 0, stream>>>(x, srcTok, counts, bufg);
  // GEMM1: [CAP,HD] @ [FD,HD]^T -> gelu -> bf16 hbuf ; 4*32*8 = 1024 blocks
  gemm256x128<HD, FD, 1, 1><<<1024, 256, 0, stream>>>(bufg, w1t, (void*)hbuf);
  // GEMM2: [CAP,FD] @ [HD,FD]^T -> bf16 partials (split-K=2) ; 4*8*8*2 = 512 blocks
  gemm256x128<FD, HD, 2, 2><<<512, 256, 0, stream>>>(hbuf, w2t, (void*)ybuf);
  scatter_kernel<<<NTOK, 128, 0, stream>>>(ybuf, te, rankA, ew, bias, out);
}